// Round 1
// baseline (109.500 us; speedup 1.0000x reference)
//
#include <hip/hip_runtime.h>
#include <math.h>

#define B_ 16
#define C_ 4
#define H_ 64
#define W_ 64
#define M_ 2048

// xt layout: [b][j][i][c][2]  (j = column index, i = row index, c = coil, re/im)
// One thread per (b, j, i): writes 8 contiguous floats (coalesced), reads strided
// (absorbed by L2; total data is only 4 MB).
__global__ __launch_bounds__(256) void transpose_kernel(
    const float* __restrict__ xr, const float* __restrict__ xi,
    float* __restrict__ xt) {
  int idx = blockIdx.x * 256 + threadIdx.x;
  int i = idx & 63;
  int j = (idx >> 6) & 63;
  int b = idx >> 12;
  float v[8];
#pragma unroll
  for (int c = 0; c < 4; ++c) {
    int src = ((b * 4 + c) * 64 + i) * 64 + j;
    v[c * 2] = xr[src];
    v[c * 2 + 1] = xi[src];
  }
  float4* dst = reinterpret_cast<float4*>(xt + ((size_t)((b * 64 + j) * 64 + i)) * 8);
  dst[0] = make_float4(v[0], v[1], v[2], v[3]);
  dst[1] = make_float4(v[4], v[5], v[6], v[7]);
}

// Workgroup = (frame b, block of 64 m-values). 8 waves; wave w owns rows
// [8w, 8w+8). Lane l owns m = mblk*64 + l. All lanes of a wave read the SAME
// x address each step (wave-uniform) -> scalar loads / broadcast.
// Separable twiddles via complex recurrence:
//   v_j = exp(-i*kx*(j-32)),  v_0 = exp(+i*32kx), v_{j+1} = v_j * exp(-i*kx)
//   w_i = exp(-i*ky*(i-32)) applied in the epilogue, same recurrence trick.
__global__ __launch_bounds__(512, 4) void nufft_kernel(
    const float* __restrict__ xt, const float* __restrict__ traj,
    float* __restrict__ out) {
  const int b    = blockIdx.x >> 5;
  const int mblk = blockIdx.x & 31;
  const int lane = threadIdx.x & 63;
  const int wave = threadIdx.x >> 6;
  const int m = mblk * 64 + lane;

  const float ky = traj[((size_t)b * M_ + m) * 2 + 0];
  const float kx = traj[((size_t)b * M_ + m) * 2 + 1];

  // column twiddle recurrence setup
  float sx, cx;
  sincosf(kx, &sx, &cx);
  const float uxr = cx, uxi = -sx;          // exp(-i*kx)
  float s0, c0;
  sincosf(32.0f * kx, &s0, &c0);
  float vr = c0, vi = s0;                   // v_0 = exp(+i*32*kx)

  const int wuni = __builtin_amdgcn_readfirstlane(wave);  // force wave-uniform
  const int i0 = wuni * 8;
  const float* xb = xt + (size_t)b * (64 * 64 * 8) + (size_t)i0 * 8;

  float accr[8][4];
  float acci[8][4];
#pragma unroll
  for (int i = 0; i < 8; ++i)
#pragma unroll
    for (int c = 0; c < 4; ++c) { accr[i][c] = 0.0f; acci[i][c] = 0.0f; }

  for (int j = 0; j < 64; ++j) {
    const float* xj = xb + (size_t)j * (64 * 8);
#pragma unroll
    for (int i = 0; i < 8; ++i) {
#pragma unroll
      for (int c = 0; c < 4; ++c) {
        const float xre = xj[i * 8 + c * 2];
        const float xim = xj[i * 8 + c * 2 + 1];
        accr[i][c] = fmaf(vr, xre, fmaf(-vi, xim, accr[i][c]));
        acci[i][c] = fmaf(vr, xim, fmaf(vi, xre, acci[i][c]));
      }
    }
    const float nvr = fmaf(vr, uxr, -(vi * uxi));
    const float nvi = fmaf(vr, uxi, vi * uxr);
    vr = nvr;
    vi = nvi;
  }

  // row twiddle w_i = exp(-i*ky*(i-32)), i = i0..i0+7
  float sy, cy;
  sincosf(ky, &sy, &cy);
  const float uyr = cy, uyi = -sy;          // exp(-i*ky)
  float sw, cw;
  sincosf(ky * (float)(32 - i0), &sw, &cw); // exp(-i*ky*(i0-32)) = (cos, sin) of ky*(32-i0)
  float wr = cw, wi = sw;

  float yr[4] = {0.f, 0.f, 0.f, 0.f};
  float yim[4] = {0.f, 0.f, 0.f, 0.f};
#pragma unroll
  for (int i = 0; i < 8; ++i) {
#pragma unroll
    for (int c = 0; c < 4; ++c) {
      yr[c]  = fmaf(wr, accr[i][c], fmaf(-wi, acci[i][c], yr[c]));
      yim[c] = fmaf(wr, acci[i][c], fmaf(wi, accr[i][c], yim[c]));
    }
    const float nwr = fmaf(wr, uyr, -(wi * uyi));
    const float nwi = fmaf(wr, uyi, wi * uyr);
    wr = nwr;
    wi = nwi;
  }

  // reduce the 8 row-block partials per m through LDS
  __shared__ float red[8][64][8];
#pragma unroll
  for (int c = 0; c < 4; ++c) {
    red[wave][lane][c * 2] = yr[c];
    red[wave][lane][c * 2 + 1] = yim[c];
  }
  __syncthreads();

  const int t = threadIdx.x;
  const int mm = t >> 3;  // 0..63
  const int k = t & 7;    // c*2 + ri
  float s = 0.0f;
#pragma unroll
  for (int w8 = 0; w8 < 8; ++w8) s += red[w8][mm][k];
  const int c = k >> 1;
  const int ri = k & 1;
  out[(((size_t)b * C_ + c) * M_ + (size_t)(mblk * 64 + mm)) * 2 + ri] = s;
}

extern "C" void kernel_launch(void* const* d_in, const int* in_sizes, int n_in,
                              void* d_out, int out_size, void* d_ws, size_t ws_size,
                              hipStream_t stream) {
  const float* xr = (const float*)d_in[0];
  const float* xi = (const float*)d_in[1];
  const float* traj = (const float*)d_in[2];
  float* out = (float*)d_out;
  float* xt = (float*)d_ws;  // needs B*H*W*C*2*4 = 2 MB of workspace

  transpose_kernel<<<(B_ * H_ * W_) / 256, 256, 0, stream>>>(xr, xi, xt);
  nufft_kernel<<<B_ * (M_ / 64), 512, 0, stream>>>(xt, traj, out);
}

// Round 4
// 89.027 us; speedup vs baseline: 1.2300x; 1.2300x over previous
//
#include <hip/hip_runtime.h>
#include <hip/hip_fp16.h>
#include <math.h>

#define B_ 16
#define C_ 4
#define M_ 2048

typedef short bf16x8 __attribute__((ext_vector_type(8)));
typedef float f32x4 __attribute__((ext_vector_type(4)));

__device__ inline unsigned short f2bf(float f) {
  union { float f; unsigned u; } v; v.f = f;
  unsigned r = v.u + 0x7fffu + ((v.u >> 16) & 1u);
  return (unsigned short)(r >> 16);
}

// B'[b][n][k] bf16, n = c*128 + i*2 + ri, k in [0,128).
//   ri=0: k<64 -> xr[c,i,j=k]    k>=64 -> -xi[c,i,j=k-64]
//   ri=1: k<64 -> xi[c,i,j=k]    k>=64 ->  xr[c,i,j=k-64]
// One thread per element — maximally simple, coalesced in k.
__global__ __launch_bounds__(256) void prep_kernel(const float* __restrict__ xr,
                                                   const float* __restrict__ xi,
                                                   unsigned short* __restrict__ Bp) {
  const int id = blockIdx.x * 256 + threadIdx.x;  // 2^20 threads total
  const int k = id & 127;
  const int n = (id >> 7) & 511;
  const int b = id >> 16;
  const int ri = n & 1, i = (n >> 1) & 63, c = n >> 7;
  const int j = k & 63;
  const int src = ((b * 4 + c) * 64 + i) * 64 + j;
  float v;
  if (k < 64) v = ri ? xi[src] : xr[src];
  else        v = ri ? xr[src] : -xi[src];
  Bp[(size_t)(b * 512 + n) * 128 + k] = f2bf(v);
}

// Block = (frame b, 128-m tile), 512 threads = 8 waves, wave = (mhalf*4 + c).
// MFMA core (verified m92 pattern): A[m=lane&15][k=quad*8+j] from LDS,
// B[k][n=lane&15] from VGPRs, D row=quad*4+reg, col=lane&15.
// P' is round-tripped through LDS with that exact D mapping; the epilogue is
// a layout-assumption-free serial fp32 loop.
__global__ __launch_bounds__(512, 2) void gemm_kernel(const unsigned short* __restrict__ Bp,
                                                      const float* __restrict__ traj,
                                                      float* __restrict__ out) {
  const int b = blockIdx.x >> 4;
  const int m0 = (blockIdx.x & 15) * 128;
  const int tid = threadIdx.x;
  const int lane = tid & 63;
  const int wave = tid >> 6;
  const int c = wave & 3;
  const int mhalf = wave >> 2;
  const int col = lane & 15;
  const int quad = lane >> 4;

  __shared__ __align__(16) unsigned short ExS[128][136];  // [m][k] bf16 twiddles
  __shared__ __align__(16) __half2 EyS[128][65];          // [m][i] (re,im) f16
  __shared__ float PS[8][16][130];                        // per-wave P' tile [row][n]
  __shared__ float2 red[128][4];                          // epilogue partials

  // ---- B' fragments: load once, keep in VGPRs.
  bf16x8 bfrag[8][4];
  {
    const unsigned short* base = Bp + (size_t)(b * 512 + c * 128) * 128;
#pragma unroll
    for (int nt = 0; nt < 8; ++nt)
#pragma unroll
      for (int ks = 0; ks < 4; ++ks)
        bfrag[nt][ks] = *(const bf16x8*)(base + (nt * 16 + col) * 128 + ks * 32 + quad * 8);
  }

  // ---- Twiddle generation into LDS (R1-verified recurrence convention).
  {
    const int mh = tid >> 2;         // 0..127
    const int j0 = (tid & 3) * 16;   // 16-step segment
    const int mg = m0 + mh;
    const float ky = traj[((size_t)b * M_ + mg) * 2 + 0];
    const float kx = traj[((size_t)b * M_ + mg) * 2 + 1];
    float sa, ca, su, cu;
    // Ex[m][j] = exp(-i*kx*(j-32)); re at k=j, im at k=64+j
    sincosf(kx * (float)(j0 - 32), &sa, &ca);
    float vr = ca, vi = -sa;
    sincosf(kx, &su, &cu);
    const float ur = cu, ui = -su;
#pragma unroll
    for (int s = 0; s < 16; ++s) {
      ExS[mh][j0 + s] = f2bf(vr);
      ExS[mh][64 + j0 + s] = f2bf(vi);
      const float nvr = fmaf(vr, ur, -(vi * ui));
      const float nvi = fmaf(vr, ui, vi * ur);
      vr = nvr; vi = nvi;
    }
    // Ey[m][i] = exp(-i*ky*(i-32))
    sincosf(ky * (float)(j0 - 32), &sa, &ca);
    float wr = ca, wi = -sa;
    sincosf(ky, &su, &cu);
    const float pr = cu, pi = -su;
#pragma unroll
    for (int s = 0; s < 16; ++s) {
      EyS[mh][j0 + s] = __floats2half2_rn(wr, wi);
      const float nwr = fmaf(wr, pr, -(wi * pi));
      const float nwi = fmaf(wr, pi, wi * pr);
      wr = nwr; wi = nwi;
    }
  }
  __syncthreads();

  for (int s = 0; s < 4; ++s) {
    const int mt = mhalf * 4 + s;

    // A fragments from LDS
    bf16x8 af[4];
#pragma unroll
    for (int ks = 0; ks < 4; ++ks)
      af[ks] = *(const bf16x8*)(&ExS[mt * 16 + col][ks * 32 + quad * 8]);

    f32x4 acc[8];
#pragma unroll
    for (int nt = 0; nt < 8; ++nt) acc[nt] = (f32x4){0.f, 0.f, 0.f, 0.f};

#pragma unroll
    for (int ks = 0; ks < 4; ++ks)
#pragma unroll
      for (int nt = 0; nt < 8; ++nt)
        acc[nt] = __builtin_amdgcn_mfma_f32_16x16x32_bf16(af[ks], bfrag[nt][ks], acc[nt], 0, 0, 0);

    __syncthreads();  // A: previous step finished reading PS/red

    // P' -> LDS with the verified C/D mapping
#pragma unroll
    for (int nt = 0; nt < 8; ++nt)
#pragma unroll
      for (int r = 0; r < 4; ++r)
        PS[wave][quad * 4 + r][nt * 16 + col] = acc[nt][r];

    __syncthreads();  // B: PS ready

    // Serial epilogue: thread = (mh2 in [0,32), c, i-quarter q)
    {
      const int p = tid >> 2;        // 0..127
      const int q = tid & 3;
      const int pc = p & 3;
      const int mh2 = p >> 2;        // 0..31
      const int g = mh2 >> 4;        // which mhalf group
      const int rowT = mh2 & 15;
      const int w = g * 4 + pc;      // source wave for this (g, c)
      const int m_local = (g * 4 + s) * 16 + rowT;
      float yr = 0.f, yi = 0.f;
      for (int ii = q * 16; ii < q * 16 + 16; ++ii) {
        const float pre = PS[w][rowT][2 * ii + 0];  // Pr at i=ii
        const float pim = PS[w][rowT][2 * ii + 1];  // Pi at i=ii
        const __half2 e = EyS[m_local][ii];
        const float er = __low2float(e), ei = __high2float(e);
        yr = fmaf(er, pre, fmaf(-ei, pim, yr));
        yi = fmaf(er, pim, fmaf(ei, pre, yi));
      }
      red[p][q] = make_float2(yr, yi);
    }

    __syncthreads();  // C: partials ready

    if (tid < 256) {
      const int p = tid >> 1;
      const int ro = tid & 1;
      const int pc = p & 3;
      const int mh2 = p >> 2;
      const int g = mh2 >> 4;
      const int rowT = mh2 & 15;
      const int m_glob = m0 + (g * 4 + s) * 16 + rowT;
      float sum = 0.f;
#pragma unroll
      for (int q = 0; q < 4; ++q) sum += ro ? red[p][q].y : red[p][q].x;
      out[((size_t)(b * 4 + pc) * M_ + m_glob) * 2 + ro] = sum;
    }
  }
}

extern "C" void kernel_launch(void* const* d_in, const int* in_sizes, int n_in,
                              void* d_out, int out_size, void* d_ws, size_t ws_size,
                              hipStream_t stream) {
  const float* xr = (const float*)d_in[0];
  const float* xi = (const float*)d_in[1];
  const float* traj = (const float*)d_in[2];
  float* out = (float*)d_out;
  unsigned short* Bp = (unsigned short*)d_ws;  // 16*512*128 bf16 = 2 MB

  prep_kernel<<<(1 << 20) / 256, 256, 0, stream>>>(xr, xi, Bp);
  gemm_kernel<<<B_ * 16, 512, 0, stream>>>(Bp, traj, out);
}